// Round 3
// baseline (12269.788 us; speedup 1.0000x reference)
//
#include <hip/hip_runtime.h>
#include <hip/hip_bf16.h>
#include <stdint.h>

typedef __bf16 bf16;
typedef __bf16 bf16x8 __attribute__((ext_vector_type(8)));
typedef float floatx4 __attribute__((ext_vector_type(4)));

#define T_STEPS 512
#define BATCH   64
#define HID     1024
#define GN      3072      // 3 gates * HID
#define KDIM    1024
#define TB      (T_STEPS*BATCH)   // 32768
#define SROW    1032      // padded LDS row stride (elements)

#define MFMA16 __builtin_amdgcn_mfma_f32_16x16x32_bf16

__device__ __forceinline__ float sigmoidf_(float x) {
  return 1.0f / (1.0f + __expf(-x));
}

// one-RT flag read: 4 split counters at 64B stride, coherent (IC) loads, no sleep
__device__ __forceinline__ uint32_t flag_sum4(const uint32_t* p) {
  uint32_t a, b, c, d;
  asm volatile(
      "global_load_dword %0, %4, off sc0 sc1\n\t"
      "global_load_dword %1, %4, off offset:64 sc0 sc1\n\t"
      "global_load_dword %2, %4, off offset:128 sc0 sc1\n\t"
      "global_load_dword %3, %4, off offset:192 sc0 sc1\n\t"
      "s_waitcnt vmcnt(0)"
      : "=v"(a), "=v"(b), "=v"(c), "=v"(d) : "v"(p) : "memory");
  return a + b + c + d;
}

__device__ __forceinline__ void wave_drain_vm() {
  asm volatile("s_waitcnt vmcnt(0)" ::: "memory");
}
__device__ __forceinline__ void wave_drain_lds() {
  asm volatile("s_waitcnt lgkmcnt(0)" ::: "memory");
}

// ---------------- small prep kernels ----------------

__global__ void cvt_f32_to_bf16(const float* __restrict__ src, bf16* __restrict__ dst, int n4) {
  int i = blockIdx.x * blockDim.x + threadIdx.x;
  if (i < n4) {
    float4 v = ((const float4*)src)[i];
    union { bf16 h[4]; uint2 u; } p;
    p.h[0] = (bf16)v.x; p.h[1] = (bf16)v.y; p.h[2] = (bf16)v.z; p.h[3] = (bf16)v.w;
    ((uint2*)dst)[i] = p.u;
  }
}

__global__ void combine_bias(const float* __restrict__ a, const float* __restrict__ b,
                             float* __restrict__ o, int n) {
  int i = blockIdx.x * blockDim.x + threadIdx.x;
  if (i < n) o[i] = a[i] + b[i];
}

__global__ void sigmoid_vec(const float* __restrict__ f, float* __restrict__ o, int n) {
  int i = blockIdx.x * blockDim.x + threadIdx.x;
  if (i < n) o[i] = sigmoidf_(f[i]);
}

__global__ void zero_words(uint32_t* __restrict__ p, int n) {
  int i = blockIdx.x * blockDim.x + threadIdx.x;
  if (i < n) p[i] = 0u;
}

// ---------------- big GEMM: C[M][3072] = A[M][1024] @ W[3072][1024]^T + bias ----------------

__global__ __launch_bounds__(256) void gemm_nt_bias(
    const bf16* __restrict__ A, const bf16* __restrict__ W,
    const float* __restrict__ bias, bf16* __restrict__ C)
{
  __shared__ __align__(16) bf16 As[128][72];
  __shared__ __align__(16) bf16 Bs[128][72];
  const int tid  = threadIdx.x;
  const int lane = tid & 63;
  const int wave = tid >> 6;
  const int wm = (wave >> 1) * 64;
  const int wn = (wave & 1) * 64;
  const size_t m0 = (size_t)blockIdx.x * 128;
  const size_t n0 = (size_t)blockIdx.y * 128;
  const int fr = lane & 15, fk = (lane >> 4) * 8;

  floatx4 acc[4][4] = {};

  for (int k0 = 0; k0 < KDIM; k0 += 64) {
#pragma unroll
    for (int i = 0; i < 4; ++i) {
      int idx = tid + i * 256;
      int row = idx >> 3, seg = idx & 7;
      *(uint4*)&As[row][seg * 8] = *(const uint4*)(A + (m0 + row) * KDIM + k0 + seg * 8);
      *(uint4*)&Bs[row][seg * 8] = *(const uint4*)(W + (n0 + row) * KDIM + k0 + seg * 8);
    }
    __syncthreads();
#pragma unroll
    for (int ks = 0; ks < 2; ++ks) {
      bf16x8 af[4], bv[4];
#pragma unroll
      for (int i = 0; i < 4; ++i) af[i] = *(const bf16x8*)&As[wm + i * 16 + fr][ks * 32 + fk];
#pragma unroll
      for (int j = 0; j < 4; ++j) bv[j] = *(const bf16x8*)&Bs[wn + j * 16 + fr][ks * 32 + fk];
#pragma unroll
      for (int i = 0; i < 4; ++i)
#pragma unroll
        for (int j = 0; j < 4; ++j)
          acc[i][j] = MFMA16(af[i], bv[j], acc[i][j], 0, 0, 0);
    }
    __syncthreads();
  }

  const int col0 = lane & 15, row0 = (lane >> 4) * 4;
#pragma unroll
  for (int j = 0; j < 4; ++j) {
    const size_t n = n0 + wn + j * 16 + col0;
    const float bval = bias[n];
#pragma unroll
    for (int i = 0; i < 4; ++i) {
#pragma unroll
      for (int r = 0; r < 4; ++r) {
        const size_t m = m0 + wm + i * 16 + row0 + r;
        C[m * GN + n] = (bf16)(acc[i][j][r] + bval);
      }
    }
  }
}

// ---------------- fused persistent 2-layer recurrence ----------------
// grid = 192 blocks x 256 threads, 1 block/CU (LDS ~135 KB).
//  blocks   0..63  : layer-0 role. jt (16 j-cols), R0-slice [48][1024] in LDS.
//  blocks 64..191  : layer-1 role. jt2 (8 j-cols), W1-slice+R1-slice in LDS,
//                    runs one step behind layer 0 (pipelined); W1 projection is
//                    folded in, so no GEMM1 / Gx1 buffer exists.
// Waves are autonomous after init: each wave spins on split arrival counters
// (coherent dword loads), loads A direct from global (32 loads in flight),
// computes MFMAs from LDS B-slices, publishes h via coherent 8B stores,
// drains vmcnt, and bumps its counter word. L0 never waits on L1; '<' spins
// are monotonic => replay-safe and resilient to partial residency.

__global__ __launch_bounds__(256) void fused_persist(
    const bf16* __restrict__ R0,     // [3072][1024]
    const bf16* __restrict__ Gx0,    // [512][64][3072] x-proj + biases (layer 0)
    const float* __restrict__ fg0,   // [1024] sigmoid(f0)
    const bf16* __restrict__ W1,     // [3072][1024]
    const bf16* __restrict__ R1,     // [3072][1024]
    const float* __restrict__ bias1, // [3072] bi1+bh1
    const float* __restrict__ fg1,   // [1024] sigmoid(f1)
    const bf16* __restrict__ zb,     // [64][1024] zeros
    bf16* __restrict__ h0buf,        // [512][64][1024]
    bf16* __restrict__ h1buf,        // [512][64][1024]
    float* __restrict__ outp,        // [512][64][1024] f32
    float* __restrict__ c0s,         // [64][1024]
    float* __restrict__ c1s,         // [64][1024]
    uint32_t* __restrict__ cnt0,     // [512][64] words (4 used per step @ stride 16)
    uint32_t* __restrict__ cnt1)     // [512][64] words
{
  __shared__ __align__(16) bf16 S[64 * SROW];        // 132096 B
  __shared__ __align__(16) bf16 Ht[4][16][24];       // 3072 B transpose tiles
  const int tid  = threadIdx.x;
  const int lane = tid & 63;
  const int wave = tid >> 6;
  const int fr = lane & 15, fk = (lane >> 4) * 8;
  const int brow0 = wave * 16 + (lane >> 4) * 4;
  const int bid = blockIdx.x;

  if (bid < 64) {
    // =================== layer-0 role ===================
    const int jt = ((bid & 7) << 3) | (bid >> 3);   // XCD swizzle for Gx locality
    // stage R0 rows (i/o/z at this j-tile)
#pragma unroll
    for (int i = 0; i < 24; ++i) {
      int idx = tid + i * 256;
      int row = idx >> 7, seg = idx & 127;
      int g = row >> 4, jj = row & 15;
      *(uint4*)&S[row * SROW + seg * 8] =
          *(const uint4*)(R0 + ((size_t)g * HID + jt * 16 + jj) * KDIM + seg * 8);
    }
    __syncthreads();

    const int j = jt * 16 + fr;
    const float fgj = fg0[j];
    float creg[4] = {0.f, 0.f, 0.f, 0.f};
    const bf16* hprev = zb;

    for (int t = 0; t < T_STEPS; ++t) {
      // Gx prefetch (completes under the spin)
      const bf16* gx = Gx0 + (size_t)t * BATCH * GN + (size_t)brow0 * GN + j;
      float gxi[4], gxo[4], gxz[4];
#pragma unroll
      for (int r = 0; r < 4; ++r) {
        gxi[r] = (float)gx[(size_t)r * GN];
        gxo[r] = (float)gx[(size_t)r * GN + HID];
        gxz[r] = (float)gx[(size_t)r * GN + 2 * HID];
      }
      if (t > 0) {
        const uint32_t* cp = cnt0 + (size_t)(t - 1) * 64;
        while (flag_sum4(cp) < 256u) { }
      }
      // A: 32 loads all in flight (1 RT)
      const bf16* arow = hprev + (size_t)(wave * 16 + fr) * HID + fk;
      bf16x8 af[32];
#pragma unroll
      for (int ks = 0; ks < 32; ++ks) af[ks] = *(const bf16x8*)(arow + ks * 32);

      floatx4 a0 = {0.f, 0.f, 0.f, 0.f}, a1 = a0, a2 = a0;
#pragma unroll
      for (int ks = 0; ks < 32; ++ks) {
        const int kk = ks * 32 + fk;
        bf16x8 b0 = *(const bf16x8*)&S[(0  + fr) * SROW + kk];
        bf16x8 b1 = *(const bf16x8*)&S[(16 + fr) * SROW + kk];
        bf16x8 b2 = *(const bf16x8*)&S[(32 + fr) * SROW + kk];
        a0 = MFMA16(af[ks], b0, a0, 0, 0, 0);
        a1 = MFMA16(af[ks], b1, a1, 0, 0, 0);
        a2 = MFMA16(af[ks], b2, a2, 0, 0, 0);
      }

      bf16* ho = h0buf + (size_t)t * BATCH * HID;
#pragma unroll
      for (int r = 0; r < 4; ++r) {
        float ig = sigmoidf_(a0[r] + gxi[r]);
        float og = sigmoidf_(a1[r] + gxo[r]);
        float zg = sigmoidf_(a2[r] + gxz[r]);
        float c = creg[r] * fgj + zg - ig;
        creg[r] = c;
        float h = sigmoidf_(c) - og;
        Ht[wave][(lane >> 4) * 4 + r][fr] = (bf16)h;
      }
      wave_drain_lds();   // wave-local transpose tile ready
      {
        const int rr = lane >> 2, cc = lane & 3;
        uint64_t v = *(const uint64_t*)&Ht[wave][rr][cc * 4];
        __hip_atomic_store((uint64_t*)(ho + (size_t)(wave * 16 + rr) * HID + jt * 16 + cc * 4),
                           v, __ATOMIC_RELAXED, __HIP_MEMORY_SCOPE_AGENT);
      }
      wave_drain_vm();    // h stores acked at coherence point
      if (lane == 0)
        __hip_atomic_fetch_add(cnt0 + (size_t)t * 64 + (jt & 3) * 16, 1u,
                               __ATOMIC_RELAXED, __HIP_MEMORY_SCOPE_AGENT);
      hprev = ho;
    }
#pragma unroll
    for (int r = 0; r < 4; ++r)
      c0s[(size_t)(brow0 + r) * HID + j] = creg[r];

  } else {
    // =================== layer-1 role ===================
    const int jt2 = bid - 64;   // 0..127, owns j-cols [jt2*8, jt2*8+8)
    // stage: rows 0-23 = W1 (g*8+jj), 24-31 = 0, 32-55 = R1, 56-63 = 0
#pragma unroll
    for (int i = 0; i < 32; ++i) {
      int idx = tid + i * 256;
      int row = idx >> 7, seg = idx & 127;
      uint4 val = {0u, 0u, 0u, 0u};
      if (row < 24) {
        int g = row >> 3, jj = row & 7;
        val = *(const uint4*)(W1 + ((size_t)g * HID + jt2 * 8 + jj) * KDIM + seg * 8);
      } else if (row >= 32 && row < 56) {
        int rr = row - 32; int g = rr >> 3, jj = rr & 7;
        val = *(const uint4*)(R1 + ((size_t)g * HID + jt2 * 8 + jj) * KDIM + seg * 8);
      }
      *(uint4*)&S[row * SROW + seg * 8] = val;
    }
    __syncthreads();

    const int jj_ = fr & 7;
    const int j1 = jt2 * 8 + jj_;
    const float fgj = fg1[j1];
    const float bi_ = bias1[j1], bo_ = bias1[HID + j1], bz_ = bias1[2 * HID + j1];
    float creg[4] = {0.f, 0.f, 0.f, 0.f};
    const bf16* h1prev = zb;

    for (int t = 0; t < T_STEPS; ++t) {
      floatx4 a0 = {0.f, 0.f, 0.f, 0.f}, a1 = a0;

      // ---- R1 phase (h1[t-1] has a full step of slack) ----
      if (t > 0) {
        const uint32_t* cp = cnt1 + (size_t)(t - 1) * 64;
        while (flag_sum4(cp) < 512u) { }
      }
      {
        const bf16* arow = h1prev + (size_t)(wave * 16 + fr) * HID + fk;
        bf16x8 af[32];
#pragma unroll
        for (int ks = 0; ks < 32; ++ks) af[ks] = *(const bf16x8*)(arow + ks * 32);
#pragma unroll
        for (int ks = 0; ks < 32; ++ks) {
          const int kk = ks * 32 + fk;
          bf16x8 bt0 = *(const bf16x8*)&S[(32 + fr) * SROW + kk];
          bf16x8 bt1 = *(const bf16x8*)&S[(48 + fr) * SROW + kk];
          a0 = MFMA16(af[ks], bt0, a0, 0, 0, 0);
          a1 = MFMA16(af[ks], bt1, a1, 0, 0, 0);
        }
      }
      // ---- W1 phase (waits on layer-0's step t) ----
      {
        const uint32_t* cp = cnt0 + (size_t)t * 64;
        while (flag_sum4(cp) < 256u) { }
      }
      {
        const bf16* arow = h0buf + (size_t)t * BATCH * HID + (size_t)(wave * 16 + fr) * HID + fk;
        bf16x8 af[32];
#pragma unroll
        for (int ks = 0; ks < 32; ++ks) af[ks] = *(const bf16x8*)(arow + ks * 32);
#pragma unroll
        for (int ks = 0; ks < 32; ++ks) {
          const int kk = ks * 32 + fk;
          bf16x8 bt0 = *(const bf16x8*)&S[(0  + fr) * SROW + kk];
          bf16x8 bt1 = *(const bf16x8*)&S[(16 + fr) * SROW + kk];
          a0 = MFMA16(af[ks], bt0, a0, 0, 0, 0);
          a1 = MFMA16(af[ks], bt1, a1, 0, 0, 0);
        }
      }

      // ---- epilogue: tile0 cols 0-7 = i, 8-15 = o; tile1 cols 0-7 = z ----
      bf16*  ho = h1buf + (size_t)t * BATCH * HID;
      float* fo = outp  + (size_t)t * BATCH * HID;
#pragma unroll
      for (int r = 0; r < 4; ++r) {
        float oraw = __shfl_xor(a0[r], 8, 64);   // lane jj gets o-gate from lane jj+8
        float ig = sigmoidf_(a0[r] + bi_);
        float og = sigmoidf_(oraw + bo_);
        float zg = sigmoidf_(a1[r] + bz_);
        float c = creg[r] * fgj + zg - ig;
        float h = sigmoidf_(c) - og;
        if (fr < 8) {
          creg[r] = c;
          Ht[wave][(lane >> 4) * 4 + r][jj_] = (bf16)h;
          fo[(size_t)(brow0 + r) * HID + j1] = h;
        }
      }
      wave_drain_lds();
      if (lane < 32) {
        const int rr = lane >> 1, cc = lane & 1;
        uint64_t v = *(const uint64_t*)&Ht[wave][rr][cc * 4];
        __hip_atomic_store((uint64_t*)(ho + (size_t)(wave * 16 + rr) * HID + jt2 * 8 + cc * 4),
                           v, __ATOMIC_RELAXED, __HIP_MEMORY_SCOPE_AGENT);
      }
      wave_drain_vm();
      if (lane == 0)
        __hip_atomic_fetch_add(cnt1 + (size_t)t * 64 + (jt2 & 3) * 16, 1u,
                               __ATOMIC_RELAXED, __HIP_MEMORY_SCOPE_AGENT);
      h1prev = ho;
    }
    if (fr < 8) {
#pragma unroll
      for (int r = 0; r < 4; ++r)
        c1s[(size_t)(brow0 + r) * HID + j1] = creg[r];
    }
  }
}

// ---------------- finalize: h_final[2][64][1024], c_final[2][64][1024] ----------------

__global__ void finalize_kernel(const bf16* __restrict__ h0_last,
                                const float* __restrict__ out_last,
                                const float* __restrict__ c0,
                                const float* __restrict__ c1,
                                float* __restrict__ dst) {
  int i = blockIdx.x * blockDim.x + threadIdx.x;
  if (i < BATCH * HID) {
    dst[i]                      = (float)h0_last[i];
    dst[BATCH * HID + i]        = out_last[i];
    dst[2 * BATCH * HID + i]    = c0[i];
    dst[3 * BATCH * HID + i]    = c1[i];
  }
}

// ---------------- launch ----------------

extern "C" void kernel_launch(void* const* d_in, const int* in_sizes, int n_in,
                              void* d_out, int out_size, void* d_ws, size_t ws_size,
                              hipStream_t stream) {
  const float* x   = (const float*)d_in[0];
  const float* W0  = (const float*)d_in[1];
  const float* R0  = (const float*)d_in[2];
  const float* bi0 = (const float*)d_in[3];
  const float* bh0 = (const float*)d_in[4];
  const float* f0  = (const float*)d_in[5];
  const float* W1  = (const float*)d_in[6];
  const float* R1  = (const float*)d_in[7];
  const float* bi1 = (const float*)d_in[8];
  const float* bh1 = (const float*)d_in[9];
  const float* f1  = (const float*)d_in[10];
  float* out = (float*)d_out;

  char* ws = (char*)d_ws;
  size_t off = 0;
  auto alloc = [&](size_t bytes) {
    char* p = ws + off;
    off += (bytes + 255) & ~(size_t)255;
    return p;
  };
  bf16* W0b = (bf16*)alloc((size_t)GN * KDIM * 2);
  bf16* R0b = (bf16*)alloc((size_t)GN * KDIM * 2);
  bf16* W1b = (bf16*)alloc((size_t)GN * KDIM * 2);
  bf16* R1b = (bf16*)alloc((size_t)GN * KDIM * 2);
  bf16* xb  = (bf16*)alloc((size_t)TB * KDIM * 2);   // x bf16; reused as h1 buffer
  bf16* h0b = (bf16*)alloc((size_t)TB * HID * 2);
  bf16* Gx  = (bf16*)alloc((size_t)TB * GN * 2);
  float* b0c = (float*)alloc(GN * 4);
  float* b1c = (float*)alloc(GN * 4);
  float* fg0 = (float*)alloc(HID * 4);
  float* fg1 = (float*)alloc(HID * 4);
  float* c0s = (float*)alloc((size_t)BATCH * HID * 4);
  float* c1s = (float*)alloc((size_t)BATCH * HID * 4);
  // the next three must stay contiguous (zeroed in one kernel, replay-safe)
  bf16*     zb   = (bf16*)alloc((size_t)BATCH * HID * 2);        // 131072 B
  uint32_t* cnt0 = (uint32_t*)alloc((size_t)T_STEPS * 64 * 4);   // 131072 B
  uint32_t* cnt1 = (uint32_t*)alloc((size_t)T_STEPS * 64 * 4);   // 131072 B

  // --- prep ---
  {
    int n4 = GN * KDIM / 4;
    int blocks = (n4 + 255) / 256;
    cvt_f32_to_bf16<<<blocks, 256, 0, stream>>>(W0, W0b, n4);
    cvt_f32_to_bf16<<<blocks, 256, 0, stream>>>(R0, R0b, n4);
    cvt_f32_to_bf16<<<blocks, 256, 0, stream>>>(W1, W1b, n4);
    cvt_f32_to_bf16<<<blocks, 256, 0, stream>>>(R1, R1b, n4);
  }
  {
    int n4 = TB * KDIM / 4;
    cvt_f32_to_bf16<<<(n4 + 255) / 256, 256, 0, stream>>>(x, xb, n4);
  }
  combine_bias<<<(GN + 255) / 256, 256, 0, stream>>>(bi0, bh0, b0c, GN);
  combine_bias<<<(GN + 255) / 256, 256, 0, stream>>>(bi1, bh1, b1c, GN);
  sigmoid_vec<<<(HID + 255) / 256, 256, 0, stream>>>(f0, fg0, HID);
  sigmoid_vec<<<(HID + 255) / 256, 256, 0, stream>>>(f1, fg1, HID);
  {
    int nwords = (BATCH * HID * 2 + 2 * T_STEPS * 64 * 4) / 4;   // zb + cnt0 + cnt1
    zero_words<<<(nwords + 255) / 256, 256, 0, stream>>>((uint32_t*)zb, nwords);
  }

  // --- layer-0 x-projection GEMM (off the recurrent critical chain) ---
  gemm_nt_bias<<<dim3(TB / 128, GN / 128), 256, 0, stream>>>(xb, W0b, b0c, Gx);

  // --- fused 2-layer pipelined recurrence (GEMM1 folded into L1 blocks) ---
  fused_persist<<<192, 256, 0, stream>>>(R0b, Gx, fg0, W1b, R1b, b1c, fg1, zb,
                                         h0b, xb, out, c0s, c1s, cnt0, cnt1);

  // --- finals ---
  finalize_kernel<<<(BATCH * HID + 255) / 256, 256, 0, stream>>>(
      h0b + (size_t)(T_STEPS - 1) * BATCH * HID,
      out + (size_t)(T_STEPS - 1) * BATCH * HID,
      c0s, c1s,
      out + (size_t)T_STEPS * BATCH * HID);
}

// Round 4
// 10069.430 us; speedup vs baseline: 1.2185x; 1.2185x over previous
//
#include <hip/hip_runtime.h>
#include <hip/hip_bf16.h>
#include <stdint.h>

typedef __bf16 bf16;
typedef __bf16 bf16x8 __attribute__((ext_vector_type(8)));
typedef float floatx4 __attribute__((ext_vector_type(4)));
typedef unsigned int uintx4 __attribute__((ext_vector_type(4)));

#define T_STEPS 512
#define BATCH   64
#define HID     1024
#define GN      3072      // 3 gates * HID
#define KDIM    1024
#define TB      (T_STEPS*BATCH)   // 32768
#define RPAD    1032      // padded LDS row stride (elements)

#define MFMA16 __builtin_amdgcn_mfma_f32_16x16x32_bf16

__device__ __forceinline__ float sigmoidf_(float x) {
  return 1.0f / (1.0f + __expf(-x));
}

// ---------------- small prep kernels ----------------

__global__ void cvt_f32_to_bf16(const float* __restrict__ src, bf16* __restrict__ dst, int n4) {
  int i = blockIdx.x * blockDim.x + threadIdx.x;
  if (i < n4) {
    float4 v = ((const float4*)src)[i];
    union { bf16 h[4]; uint2 u; } p;
    p.h[0] = (bf16)v.x; p.h[1] = (bf16)v.y; p.h[2] = (bf16)v.z; p.h[3] = (bf16)v.w;
    ((uint2*)dst)[i] = p.u;
  }
}

__global__ void combine_bias(const float* __restrict__ a, const float* __restrict__ b,
                             float* __restrict__ o, int n) {
  int i = blockIdx.x * blockDim.x + threadIdx.x;
  if (i < n) o[i] = a[i] + b[i];
}

__global__ void sigmoid_vec(const float* __restrict__ f, float* __restrict__ o, int n) {
  int i = blockIdx.x * blockDim.x + threadIdx.x;
  if (i < n) o[i] = sigmoidf_(f[i]);
}

__global__ void zero_words(uint32_t* __restrict__ p, int n) {
  int i = blockIdx.x * blockDim.x + threadIdx.x;
  if (i < n) p[i] = 0u;
}

// ---------------- big GEMM: C[M][3072] = A[M][1024] @ W[3072][1024]^T + bias ----------------

__global__ __launch_bounds__(256) void gemm_nt_bias(
    const bf16* __restrict__ A, const bf16* __restrict__ W,
    const float* __restrict__ bias, bf16* __restrict__ C)
{
  __shared__ __align__(16) bf16 As[128][72];
  __shared__ __align__(16) bf16 Bs[128][72];
  const int tid  = threadIdx.x;
  const int lane = tid & 63;
  const int wave = tid >> 6;
  const int wm = (wave >> 1) * 64;
  const int wn = (wave & 1) * 64;
  const size_t m0 = (size_t)blockIdx.x * 128;
  const size_t n0 = (size_t)blockIdx.y * 128;
  const int fr = lane & 15, fk = (lane >> 4) * 8;

  floatx4 acc[4][4] = {};

  for (int k0 = 0; k0 < KDIM; k0 += 64) {
#pragma unroll
    for (int i = 0; i < 4; ++i) {
      int idx = tid + i * 256;
      int row = idx >> 3, seg = idx & 7;
      *(uint4*)&As[row][seg * 8] = *(const uint4*)(A + (m0 + row) * KDIM + k0 + seg * 8);
      *(uint4*)&Bs[row][seg * 8] = *(const uint4*)(W + (n0 + row) * KDIM + k0 + seg * 8);
    }
    __syncthreads();
#pragma unroll
    for (int ks = 0; ks < 2; ++ks) {
      bf16x8 af[4], bv[4];
#pragma unroll
      for (int i = 0; i < 4; ++i) af[i] = *(const bf16x8*)&As[wm + i * 16 + fr][ks * 32 + fk];
#pragma unroll
      for (int j = 0; j < 4; ++j) bv[j] = *(const bf16x8*)&Bs[wn + j * 16 + fr][ks * 32 + fk];
#pragma unroll
      for (int i = 0; i < 4; ++i)
#pragma unroll
        for (int j = 0; j < 4; ++j)
          acc[i][j] = MFMA16(af[i], bv[j], acc[i][j], 0, 0, 0);
    }
    __syncthreads();
  }

  const int col0 = lane & 15, row0 = (lane >> 4) * 4;
#pragma unroll
  for (int j = 0; j < 4; ++j) {
    const size_t n = n0 + wn + j * 16 + col0;
    const float bval = bias[n];
#pragma unroll
    for (int i = 0; i < 4; ++i) {
#pragma unroll
      for (int r = 0; r < 4; ++r) {
        const size_t m = m0 + wm + i * 16 + row0 + r;
        C[m * GN + n] = (bf16)(acc[i][j][r] + bval);
      }
    }
  }
}

// ---------------- persistent recurrent kernel (per layer) ----------------
// 64 blocks x 256 threads, 1 block/CU. R-slice (48x1024) in LDS for all steps;
// c-state in registers.
//
// Sync (contention-free, R3 lesson):
//  - publish: each wave drains its own coherent h stores (vmcnt 0), then lane 0
//    stores flg[t*256 + jt*4 + wave] = 1 (plain sc0 sc1 store; no RMW, no
//    producer barrier).
//  - wait: only wave 0 polls; lane l reads flg[(t-1)*256 + l*4 ..+3] with one
//    coherent dwordx4 (64 lanes = the whole 1KB flag row, coalesced, 1 RT),
//    exits when __all(words nonzero); s_sleep(1) backoff. __syncthreads
//    releases waves 1-3 (which have Gx loads already in flight).
//  - h_prev read: plain cached loads, 32 dwordx4 all in flight (1 RT).
//  - flags zeroed at graph replay start; values monotonic 0->1 => replay-safe.

__global__ __launch_bounds__(256, 1) void sublstm_persist(
    const bf16* __restrict__ R,      // [3072][1024]
    const bf16* __restrict__ Gx,     // [512][64][3072]  x-projection + biases
    const float* __restrict__ fg,    // [1024] sigmoid(f)
    const bf16* __restrict__ h0,     // [64][1024] zeros
    bf16* __restrict__ hout,         // [512][64][1024]
    float* __restrict__ fout,        // null, or [512][64][1024] f32
    float* __restrict__ c_out,       // [64][1024] final c
    uint32_t* __restrict__ flg)      // [512][256] one word per (step, jt, wave)
{
  __shared__ __align__(16) bf16 Rs[48][RPAD];   // 99072 B
  __shared__ __align__(16) bf16 Ht[4][16][24];  // 3072 B per-wave transpose tiles
  const int tid  = threadIdx.x;
  const int lane = tid & 63;
  const int wave = tid >> 6;          // wave owns batch rows [wave*16, wave*16+16)
  const int jt   = ((blockIdx.x & 7) << 3) | (blockIdx.x >> 3);  // XCD swizzle
  const int fr = lane & 15, fk = (lane >> 4) * 8;

  // one-time: stage the 48 R rows (gates i/o/z at this j-tile) into LDS
#pragma unroll
  for (int i = 0; i < 24; ++i) {
    int idx = tid + i * 256;
    int row = idx >> 7, seg = idx & 127;
    int g = row >> 4, jj = row & 15;
    *(uint4*)&Rs[row][seg * 8] =
        *(const uint4*)(R + ((size_t)g * HID + jt * 16 + jj) * KDIM + seg * 8);
  }

  const int j = jt * 16 + fr;
  const float fgj = fg[j];
  const int brow0 = wave * 16 + (lane >> 4) * 4;
  float creg[4] = {0.f, 0.f, 0.f, 0.f};

  __syncthreads();

  const bf16* hprev = h0;
  for (int t = 0; t < T_STEPS; ++t) {
    // ---- Gx prefetch: in flight while we wait on the flags ----
    const bf16* gx = Gx + (size_t)t * BATCH * GN + (size_t)brow0 * GN + j;
    float gxi[4], gxo[4], gxz[4];
#pragma unroll
    for (int r = 0; r < 4; ++r) {
      gxi[r] = (float)gx[(size_t)r * GN];
      gxo[r] = (float)gx[(size_t)r * GN + HID];
      gxz[r] = (float)gx[(size_t)r * GN + 2 * HID];
    }

    // ---- wait until all 64 producer blocks published h_{t-1} ----
    if (t > 0) {
      if (wave == 0) {
        const uint32_t* fp = flg + (size_t)(t - 1) * 256 + lane * 4;
        for (;;) {
          uintx4 v;
          asm volatile(
              "global_load_dwordx4 %0, %1, off sc0 sc1\n\t"
              "s_waitcnt vmcnt(0)"
              : "=v"(v) : "v"(fp) : "memory");
          if (__all((v[0] & v[1] & v[2] & v[3]) != 0u)) break;
          __builtin_amdgcn_s_sleep(1);
        }
      }
      __syncthreads();   // release waves 1-3; compiler barrier for h loads
    }

    // ---- A: all 32 loads in flight (1 IC round-trip) ----
    const bf16* arow = hprev + (size_t)(wave * 16 + fr) * HID + fk;
    bf16x8 af[32];
#pragma unroll
    for (int ks = 0; ks < 32; ++ks) af[ks] = *(const bf16x8*)(arow + ks * 32);

    floatx4 a0 = {0.f, 0.f, 0.f, 0.f}, a1 = a0, a2 = a0;
#pragma unroll
    for (int ks = 0; ks < 32; ++ks) {
      const int kk = ks * 32 + fk;
      bf16x8 b0 = *(const bf16x8*)&Rs[ 0 + fr][kk];
      bf16x8 b1 = *(const bf16x8*)&Rs[16 + fr][kk];
      bf16x8 b2 = *(const bf16x8*)&Rs[32 + fr][kk];
      a0 = MFMA16(af[ks], b0, a0, 0, 0, 0);
      a1 = MFMA16(af[ks], b1, a1, 0, 0, 0);
      a2 = MFMA16(af[ks], b2, a2, 0, 0, 0);
    }

    // ---- epilogue: gates, cell update, publish h (per-wave, no block barrier) ----
    bf16*  ho = hout + (size_t)t * BATCH * HID;
    float* fo = fout ? fout + (size_t)t * BATCH * HID : nullptr;
#pragma unroll
    for (int r = 0; r < 4; ++r) {
      float ig = sigmoidf_(a0[r] + gxi[r]);
      float og = sigmoidf_(a1[r] + gxo[r]);
      float zg = sigmoidf_(a2[r] + gxz[r]);
      float c = creg[r] * fgj + zg - ig;
      creg[r] = c;
      float h = sigmoidf_(c) - og;
      if (fo) fo[(size_t)(brow0 + r) * HID + j] = h;
      Ht[wave][(lane >> 4) * 4 + r][fr] = (bf16)h;
    }
    asm volatile("s_waitcnt lgkmcnt(0)" ::: "memory");   // wave-local transpose ready
    {
      const int rr = lane >> 2, cc = lane & 3;           // 16 rows x 4 chunks of 8B
      uint64_t v = *(const uint64_t*)&Ht[wave][rr][cc * 4];
      __hip_atomic_store((uint64_t*)(ho + (size_t)(wave * 16 + rr) * HID + jt * 16 + cc * 4),
                         v, __ATOMIC_RELAXED, __HIP_MEMORY_SCOPE_AGENT);
    }
    asm volatile("s_waitcnt vmcnt(0)" ::: "memory");     // h (and f32) stores acked
    if (lane == 0) {
      uint32_t* fp = flg + (size_t)t * 256 + jt * 4 + wave;
      uint32_t one = 1u;
      asm volatile("global_store_dword %0, %1, off sc0 sc1"
                   :: "v"(fp), "v"(one) : "memory");
    }
    hprev = ho;
  }

  // final c state
#pragma unroll
  for (int r = 0; r < 4; ++r)
    c_out[(size_t)(brow0 + r) * HID + j] = creg[r];
}

// ---------------- finalize: h_final[2][64][1024], c_final[2][64][1024] ----------------

__global__ void finalize_kernel(const bf16* __restrict__ h0_last,
                                const float* __restrict__ out_last,
                                const float* __restrict__ c0,
                                const float* __restrict__ c1,
                                float* __restrict__ dst) {
  int i = blockIdx.x * blockDim.x + threadIdx.x;
  if (i < BATCH * HID) {
    dst[i]                      = (float)h0_last[i];
    dst[BATCH * HID + i]        = out_last[i];
    dst[2 * BATCH * HID + i]    = c0[i];
    dst[3 * BATCH * HID + i]    = c1[i];
  }
}

// ---------------- launch ----------------

extern "C" void kernel_launch(void* const* d_in, const int* in_sizes, int n_in,
                              void* d_out, int out_size, void* d_ws, size_t ws_size,
                              hipStream_t stream) {
  const float* x   = (const float*)d_in[0];
  const float* W0  = (const float*)d_in[1];
  const float* R0  = (const float*)d_in[2];
  const float* bi0 = (const float*)d_in[3];
  const float* bh0 = (const float*)d_in[4];
  const float* f0  = (const float*)d_in[5];
  const float* W1  = (const float*)d_in[6];
  const float* R1  = (const float*)d_in[7];
  const float* bi1 = (const float*)d_in[8];
  const float* bh1 = (const float*)d_in[9];
  const float* f1  = (const float*)d_in[10];
  float* out = (float*)d_out;

  char* ws = (char*)d_ws;
  size_t off = 0;
  auto alloc = [&](size_t bytes) {
    char* p = ws + off;
    off += (bytes + 255) & ~(size_t)255;
    return p;
  };
  bf16* W0b = (bf16*)alloc((size_t)GN * KDIM * 2);
  bf16* R0b = (bf16*)alloc((size_t)GN * KDIM * 2);
  bf16* W1b = (bf16*)alloc((size_t)GN * KDIM * 2);
  bf16* R1b = (bf16*)alloc((size_t)GN * KDIM * 2);
  bf16* xb  = (bf16*)alloc((size_t)TB * KDIM * 2);   // x bf16; reused as h1 buffer
  bf16* h0b = (bf16*)alloc((size_t)TB * HID * 2);
  bf16* Gx  = (bf16*)alloc((size_t)TB * GN * 2);
  float* b0c = (float*)alloc(GN * 4);
  float* b1c = (float*)alloc(GN * 4);
  float* fg0 = (float*)alloc(HID * 4);
  float* fg1 = (float*)alloc(HID * 4);
  float* c0s = (float*)alloc((size_t)BATCH * HID * 4);
  float* c1s = (float*)alloc((size_t)BATCH * HID * 4);
  // the next three must stay contiguous (zeroed in one kernel, replay-safe)
  bf16*     zb   = (bf16*)alloc((size_t)BATCH * HID * 2);          // 131072 B
  uint32_t* flg0 = (uint32_t*)alloc((size_t)T_STEPS * 256 * 4);    // 524288 B
  uint32_t* flg1 = (uint32_t*)alloc((size_t)T_STEPS * 256 * 4);    // 524288 B

  // --- prep ---
  {
    int n4 = GN * KDIM / 4;
    int blocks = (n4 + 255) / 256;
    cvt_f32_to_bf16<<<blocks, 256, 0, stream>>>(W0, W0b, n4);
    cvt_f32_to_bf16<<<blocks, 256, 0, stream>>>(R0, R0b, n4);
    cvt_f32_to_bf16<<<blocks, 256, 0, stream>>>(W1, W1b, n4);
    cvt_f32_to_bf16<<<blocks, 256, 0, stream>>>(R1, R1b, n4);
  }
  {
    int n4 = TB * KDIM / 4;
    cvt_f32_to_bf16<<<(n4 + 255) / 256, 256, 0, stream>>>(x, xb, n4);
  }
  combine_bias<<<(GN + 255) / 256, 256, 0, stream>>>(bi0, bh0, b0c, GN);
  combine_bias<<<(GN + 255) / 256, 256, 0, stream>>>(bi1, bh1, b1c, GN);
  sigmoid_vec<<<(HID + 255) / 256, 256, 0, stream>>>(f0, fg0, HID);
  sigmoid_vec<<<(HID + 255) / 256, 256, 0, stream>>>(f1, fg1, HID);
  {
    int nwords = (BATCH * HID * 2 + 2 * T_STEPS * 256 * 4) / 4;   // zb + flg0 + flg1
    zero_words<<<(nwords + 255) / 256, 256, 0, stream>>>((uint32_t*)zb, nwords);
  }

  // --- layer 0 ---
  gemm_nt_bias<<<dim3(TB / 128, GN / 128), 256, 0, stream>>>(xb, W0b, b0c, Gx);
  sublstm_persist<<<64, 256, 0, stream>>>(R0b, Gx, fg0, zb, h0b, nullptr, c0s, flg0);

  // --- layer 1 (h1 reuses xb) ---
  gemm_nt_bias<<<dim3(TB / 128, GN / 128), 256, 0, stream>>>(h0b, W1b, b1c, Gx);
  sublstm_persist<<<64, 256, 0, stream>>>(R1b, Gx, fg1, zb, xb, out, c1s, flg1);

  // --- finals ---
  finalize_kernel<<<(BATCH * HID + 255) / 256, 256, 0, stream>>>(
      h0b + (size_t)(T_STEPS - 1) * BATCH * HID,
      out + (size_t)(T_STEPS - 1) * BATCH * HID,
      c0s, c1s,
      out + (size_t)T_STEPS * BATCH * HID);
}

// Round 5
// 5204.106 us; speedup vs baseline: 2.3577x; 1.9349x over previous
//
#include <hip/hip_runtime.h>
#include <hip/hip_bf16.h>
#include <stdint.h>

typedef __bf16 bf16;
typedef __bf16 bf16x8 __attribute__((ext_vector_type(8)));
typedef float floatx4 __attribute__((ext_vector_type(4)));
typedef unsigned int uintx4 __attribute__((ext_vector_type(4)));

#define T_STEPS 512
#define BATCH   64
#define HID     1024
#define GN      3072      // 3 gates * HID
#define KDIM    1024
#define TB      (T_STEPS*BATCH)   // 32768
#define SROW    1032      // padded LDS row stride (elements)

#define MFMA16 __builtin_amdgcn_mfma_f32_16x16x32_bf16

__device__ __forceinline__ float sigmoidf_(float x) {
  return 1.0f / (1.0f + __expf(-x));
}

// ---------------- small prep kernels ----------------

__global__ void cvt_f32_to_bf16(const float* __restrict__ src, bf16* __restrict__ dst, int n4) {
  int i = blockIdx.x * blockDim.x + threadIdx.x;
  if (i < n4) {
    float4 v = ((const float4*)src)[i];
    union { bf16 h[4]; uint2 u; } p;
    p.h[0] = (bf16)v.x; p.h[1] = (bf16)v.y; p.h[2] = (bf16)v.z; p.h[3] = (bf16)v.w;
    ((uint2*)dst)[i] = p.u;
  }
}

__global__ void combine_bias(const float* __restrict__ a, const float* __restrict__ b,
                             float* __restrict__ o, int n) {
  int i = blockIdx.x * blockDim.x + threadIdx.x;
  if (i < n) o[i] = a[i] + b[i];
}

__global__ void sigmoid_vec(const float* __restrict__ f, float* __restrict__ o, int n) {
  int i = blockIdx.x * blockDim.x + threadIdx.x;
  if (i < n) o[i] = sigmoidf_(f[i]);
}

__global__ void zero_words(uint32_t* __restrict__ p, int n) {
  int i = blockIdx.x * blockDim.x + threadIdx.x;
  if (i < n) p[i] = 0u;
}

// ---------------- big GEMM: C[M][3072] = A[M][1024] @ W[3072][1024]^T + bias ----------------

__global__ __launch_bounds__(256) void gemm_nt_bias(
    const bf16* __restrict__ A, const bf16* __restrict__ W,
    const float* __restrict__ bias, bf16* __restrict__ C)
{
  __shared__ __align__(16) bf16 As[128][72];
  __shared__ __align__(16) bf16 Bs[128][72];
  const int tid  = threadIdx.x;
  const int lane = tid & 63;
  const int wave = tid >> 6;
  const int wm = (wave >> 1) * 64;
  const int wn = (wave & 1) * 64;
  const size_t m0 = (size_t)blockIdx.x * 128;
  const size_t n0 = (size_t)blockIdx.y * 128;
  const int fr = lane & 15, fk = (lane >> 4) * 8;

  floatx4 acc[4][4] = {};

  for (int k0 = 0; k0 < KDIM; k0 += 64) {
#pragma unroll
    for (int i = 0; i < 4; ++i) {
      int idx = tid + i * 256;
      int row = idx >> 3, seg = idx & 7;
      *(uint4*)&As[row][seg * 8] = *(const uint4*)(A + (m0 + row) * KDIM + k0 + seg * 8);
      *(uint4*)&Bs[row][seg * 8] = *(const uint4*)(W + (n0 + row) * KDIM + k0 + seg * 8);
    }
    __syncthreads();
#pragma unroll
    for (int ks = 0; ks < 2; ++ks) {
      bf16x8 af[4], bv[4];
#pragma unroll
      for (int i = 0; i < 4; ++i) af[i] = *(const bf16x8*)&As[wm + i * 16 + fr][ks * 32 + fk];
#pragma unroll
      for (int j = 0; j < 4; ++j) bv[j] = *(const bf16x8*)&Bs[wn + j * 16 + fr][ks * 32 + fk];
#pragma unroll
      for (int i = 0; i < 4; ++i)
#pragma unroll
        for (int j = 0; j < 4; ++j)
          acc[i][j] = MFMA16(af[i], bv[j], acc[i][j], 0, 0, 0);
    }
    __syncthreads();
  }

  const int col0 = lane & 15, row0 = (lane >> 4) * 4;
#pragma unroll
  for (int j = 0; j < 4; ++j) {
    const size_t n = n0 + wn + j * 16 + col0;
    const float bval = bias[j < 4 ? n : n];
#pragma unroll
    for (int i = 0; i < 4; ++i) {
#pragma unroll
      for (int r = 0; r < 4; ++r) {
        const size_t m = m0 + wm + i * 16 + row0 + r;
        C[m * GN + n] = (bf16)(acc[i][j][r] + bval);
      }
    }
  }
}

// ---------------- fused persistent 2-layer recurrence (v2) ----------------
// grid = 192 blocks x 256 threads, 1 block/CU (LDS 135 KB), all co-resident.
//   blocks   0..63 : layer-0 role (identical to R4's proven persist kernel).
//   blocks 64..191 : layer-1 role, 8 j-cols each; W1-slice + R1-slice in LDS;
//                    runs one step behind layer 0. GEMM1 is folded in.
// Sync = R4's contention-free scheme everywhere (R3 lesson):
//   - publish: wave drains its own coherent h stores (vmcnt 0), lane 0 plain-
//     stores its private flag word (sc0 sc1). No RMW, no producer barrier.
//   - wait: ONLY wave 0 polls, one coalesced coherent row-read per iteration,
//     s_sleep backoff; __syncthreads releases the block.
//   - L0 never waits on L1 => deadlock-free; '<'-monotonic flags => replay-safe.

__global__ __launch_bounds__(256, 1) void fused_persist(
    const bf16* __restrict__ R0,     // [3072][1024]
    const bf16* __restrict__ Gx0,    // [512][64][3072] x-proj + biases (layer 0)
    const float* __restrict__ fg0,   // [1024] sigmoid(f0)
    const bf16* __restrict__ W1,     // [3072][1024]
    const bf16* __restrict__ R1,     // [3072][1024]
    const float* __restrict__ bias1, // [3072] bi1+bh1
    const float* __restrict__ fg1,   // [1024] sigmoid(f1)
    const bf16* __restrict__ zb,     // [64][1024] zeros
    bf16* __restrict__ h0buf,        // [512][64][1024]
    bf16* __restrict__ h1buf,        // [512][64][1024]
    float* __restrict__ outp,        // [512][64][1024] f32
    float* __restrict__ c0s,         // [64][1024]
    float* __restrict__ c1s,         // [64][1024]
    uint32_t* __restrict__ flg0,     // [512][256] word per (t, jt, wave)
    uint32_t* __restrict__ flg1)     // [512][512] word per (t, jt2, wave)
{
  __shared__ __align__(16) bf16 S[64 * SROW];     // 132096 B
  __shared__ __align__(16) bf16 Ht[4][16][24];    // 3072 B per-wave transpose tiles
  const int tid  = threadIdx.x;
  const int lane = tid & 63;
  const int wave = tid >> 6;          // wave owns batch rows [wave*16, wave*16+16)
  const int fr = lane & 15, fk = (lane >> 4) * 8;
  const int brow0 = wave * 16 + (lane >> 4) * 4;
  const int bid = blockIdx.x;

  if (bid < 64) {
    // =================== layer-0 role (R4-proven) ===================
    const int jt = ((bid & 7) << 3) | (bid >> 3);   // XCD swizzle for Gx locality
#pragma unroll
    for (int i = 0; i < 24; ++i) {
      int idx = tid + i * 256;
      int row = idx >> 7, seg = idx & 127;
      int g = row >> 4, jj = row & 15;
      *(uint4*)&S[row * SROW + seg * 8] =
          *(const uint4*)(R0 + ((size_t)g * HID + jt * 16 + jj) * KDIM + seg * 8);
    }

    const int j = jt * 16 + fr;
    const float fgj = fg0[j];
    float creg[4] = {0.f, 0.f, 0.f, 0.f};
    __syncthreads();

    const bf16* hprev = zb;
    for (int t = 0; t < T_STEPS; ++t) {
      // Gx prefetch: in flight while we wait on the flags
      const bf16* gx = Gx0 + (size_t)t * BATCH * GN + (size_t)brow0 * GN + j;
      float gxi[4], gxo[4], gxz[4];
#pragma unroll
      for (int r = 0; r < 4; ++r) {
        gxi[r] = (float)gx[(size_t)r * GN];
        gxo[r] = (float)gx[(size_t)r * GN + HID];
        gxz[r] = (float)gx[(size_t)r * GN + 2 * HID];
      }

      if (t > 0) {
        if (wave == 0) {
          const uint32_t* fp = flg0 + (size_t)(t - 1) * 256 + lane * 4;
          for (;;) {
            uintx4 v;
            asm volatile(
                "global_load_dwordx4 %0, %1, off sc0 sc1\n\t"
                "s_waitcnt vmcnt(0)"
                : "=v"(v) : "v"(fp) : "memory");
            if (__all((v[0] & v[1] & v[2] & v[3]) != 0u)) break;
            __builtin_amdgcn_s_sleep(1);
          }
        }
        __syncthreads();
      }

      // A: all 32 loads in flight
      const bf16* arow = hprev + (size_t)(wave * 16 + fr) * HID + fk;
      bf16x8 af[32];
#pragma unroll
      for (int ks = 0; ks < 32; ++ks) af[ks] = *(const bf16x8*)(arow + ks * 32);

      floatx4 a0 = {0.f, 0.f, 0.f, 0.f}, a1 = a0, a2 = a0;
#pragma unroll
      for (int ks = 0; ks < 32; ++ks) {
        const int kk = ks * 32 + fk;
        bf16x8 b0 = *(const bf16x8*)&S[( 0 + fr) * SROW + kk];
        bf16x8 b1 = *(const bf16x8*)&S[(16 + fr) * SROW + kk];
        bf16x8 b2 = *(const bf16x8*)&S[(32 + fr) * SROW + kk];
        a0 = MFMA16(af[ks], b0, a0, 0, 0, 0);
        a1 = MFMA16(af[ks], b1, a1, 0, 0, 0);
        a2 = MFMA16(af[ks], b2, a2, 0, 0, 0);
      }

      bf16* ho = h0buf + (size_t)t * BATCH * HID;
#pragma unroll
      for (int r = 0; r < 4; ++r) {
        float ig = sigmoidf_(a0[r] + gxi[r]);
        float og = sigmoidf_(a1[r] + gxo[r]);
        float zg = sigmoidf_(a2[r] + gxz[r]);
        float c = creg[r] * fgj + zg - ig;
        creg[r] = c;
        float h = sigmoidf_(c) - og;
        Ht[wave][(lane >> 4) * 4 + r][fr] = (bf16)h;
      }
      asm volatile("s_waitcnt lgkmcnt(0)" ::: "memory");
      {
        const int rr = lane >> 2, cc = lane & 3;
        uint64_t v = *(const uint64_t*)&Ht[wave][rr][cc * 4];
        __hip_atomic_store((uint64_t*)(ho + (size_t)(wave * 16 + rr) * HID + jt * 16 + cc * 4),
                           v, __ATOMIC_RELAXED, __HIP_MEMORY_SCOPE_AGENT);
      }
      asm volatile("s_waitcnt vmcnt(0)" ::: "memory");
      if (lane == 0) {
        uint32_t* fp = flg0 + (size_t)t * 256 + jt * 4 + wave;
        uint32_t one = 1u;
        asm volatile("global_store_dword %0, %1, off sc0 sc1"
                     :: "v"(fp), "v"(one) : "memory");
      }
      hprev = ho;
    }
#pragma unroll
    for (int r = 0; r < 4; ++r)
      c0s[(size_t)(brow0 + r) * HID + j] = creg[r];

  } else {
    // =================== layer-1 role ===================
    const int jt2 = bid - 64;   // 0..127, owns j-cols [jt2*8, jt2*8+8)
    // stage rows: 0-23 = W1 (g*8+jj), 24-31 = 0, 32-55 = R1, 56-63 = 0
#pragma unroll
    for (int i = 0; i < 32; ++i) {
      int idx = tid + i * 256;
      int row = idx >> 7, seg = idx & 127;
      uint4 val = {0u, 0u, 0u, 0u};
      if (row < 24) {
        int g = row >> 3, jj = row & 7;
        val = *(const uint4*)(W1 + ((size_t)g * HID + jt2 * 8 + jj) * KDIM + seg * 8);
      } else if (row >= 32 && row < 56) {
        int rr = row - 32; int g = rr >> 3, jj = rr & 7;
        val = *(const uint4*)(R1 + ((size_t)g * HID + jt2 * 8 + jj) * KDIM + seg * 8);
      }
      *(uint4*)&S[row * SROW + seg * 8] = val;
    }
    __syncthreads();

    const int jj_ = fr & 7;
    const int j1 = jt2 * 8 + jj_;
    const float fgj = fg1[j1];
    const float bi_ = bias1[j1], bo_ = bias1[HID + j1], bz_ = bias1[2 * HID + j1];
    float creg[4] = {0.f, 0.f, 0.f, 0.f};
    const bf16* h1prev = zb;

    for (int t = 0; t < T_STEPS; ++t) {
      // ---- wait for h0[t] (published by layer-0 blocks) ----
      if (wave == 0) {
        const uint32_t* fp = flg0 + (size_t)t * 256 + lane * 4;
        for (;;) {
          uintx4 v;
          asm volatile(
              "global_load_dwordx4 %0, %1, off sc0 sc1\n\t"
              "s_waitcnt vmcnt(0)"
              : "=v"(v) : "v"(fp) : "memory");
          if (__all((v[0] & v[1] & v[2] & v[3]) != 0u)) break;
          __builtin_amdgcn_s_sleep(2);
        }
      }
      __syncthreads();

      floatx4 a0 = {0.f, 0.f, 0.f, 0.f}, a1 = a0;

      // ---- W1 phase: A = h0[t] (off the h1 recurrence chain) ----
      {
        const bf16* arow = h0buf + (size_t)t * BATCH * HID + (size_t)(wave * 16 + fr) * HID + fk;
        bf16x8 af[32];
#pragma unroll
        for (int ks = 0; ks < 32; ++ks) af[ks] = *(const bf16x8*)(arow + ks * 32);
#pragma unroll
        for (int ks = 0; ks < 32; ++ks) {
          const int kk = ks * 32 + fk;
          bf16x8 b0 = *(const bf16x8*)&S[( 0 + fr) * SROW + kk];
          bf16x8 b1 = *(const bf16x8*)&S[(16 + fr) * SROW + kk];
          a0 = MFMA16(af[ks], b0, a0, 0, 0, 0);
          a1 = MFMA16(af[ks], b1, a1, 0, 0, 0);
        }
      }

      // ---- wait for h1[t-1] (published by layer-1 blocks) ----
      if (t > 0) {
        if (wave == 0) {
          const uint32_t* fp = flg1 + (size_t)(t - 1) * 512 + lane * 8;
          for (;;) {
            uintx4 v0, v1;
            asm volatile(
                "global_load_dwordx4 %0, %2, off sc0 sc1\n\t"
                "global_load_dwordx4 %1, %2, off offset:16 sc0 sc1\n\t"
                "s_waitcnt vmcnt(0)"
                : "=v"(v0), "=v"(v1) : "v"(fp) : "memory");
            uint32_t m = v0[0] & v0[1] & v0[2] & v0[3] & v1[0] & v1[1] & v1[2] & v1[3];
            if (__all(m != 0u)) break;
            __builtin_amdgcn_s_sleep(1);
          }
        }
        __syncthreads();
      }

      // ---- R1 phase: A = h1[t-1] ----
      {
        const bf16* arow = h1prev + (size_t)(wave * 16 + fr) * HID + fk;
        bf16x8 af[32];
#pragma unroll
        for (int ks = 0; ks < 32; ++ks) af[ks] = *(const bf16x8*)(arow + ks * 32);
#pragma unroll
        for (int ks = 0; ks < 32; ++ks) {
          const int kk = ks * 32 + fk;
          bf16x8 b0 = *(const bf16x8*)&S[(32 + fr) * SROW + kk];
          bf16x8 b1 = *(const bf16x8*)&S[(48 + fr) * SROW + kk];
          a0 = MFMA16(af[ks], b0, a0, 0, 0, 0);
          a1 = MFMA16(af[ks], b1, a1, 0, 0, 0);
        }
      }

      // ---- epilogue: tile0 = [i(8) | o(8)], tile1 = [z(8) | -] ----
      bf16* ho = h1buf + (size_t)t * BATCH * HID;
      float hreg[4];
#pragma unroll
      for (int r = 0; r < 4; ++r) {
        float oraw = __shfl_xor(a0[r], 8, 64);   // lane jj gets o-gate from lane jj+8
        float ig = sigmoidf_(a0[r] + bi_);
        float og = sigmoidf_(oraw + bo_);
        float zg = sigmoidf_(a1[r] + bz_);
        float c = creg[r] * fgj + zg - ig;
        float h = sigmoidf_(c) - og;
        hreg[r] = h;
        if (fr < 8) {
          creg[r] = c;
          Ht[wave][(lane >> 4) * 4 + r][jj_] = (bf16)h;
        }
      }
      asm volatile("s_waitcnt lgkmcnt(0)" ::: "memory");
      if (lane < 32) {
        const int rr = lane >> 1, cc = lane & 1;
        uint64_t v = *(const uint64_t*)&Ht[wave][rr][cc * 4];
        __hip_atomic_store((uint64_t*)(ho + (size_t)(wave * 16 + rr) * HID + jt2 * 8 + cc * 4),
                           v, __ATOMIC_RELAXED, __HIP_MEMORY_SCOPE_AGENT);
      }
      asm volatile("s_waitcnt vmcnt(0)" ::: "memory");
      if (lane == 0) {
        uint32_t* fp = flg1 + (size_t)t * 512 + jt2 * 4 + wave;
        uint32_t one = 1u;
        asm volatile("global_store_dword %0, %1, off sc0 sc1"
                     :: "v"(fp), "v"(one) : "memory");
      }
      // f32 out stores: after the flag, off the publish critical path
      if (fr < 8) {
        float* fo = outp + (size_t)t * BATCH * HID;
#pragma unroll
        for (int r = 0; r < 4; ++r)
          fo[(size_t)(brow0 + r) * HID + j1] = hreg[r];
      }
      h1prev = ho;
    }
    if (fr < 8) {
#pragma unroll
      for (int r = 0; r < 4; ++r)
        c1s[(size_t)(brow0 + r) * HID + j1] = creg[r];
    }
  }
}

// ---------------- finalize: h_final[2][64][1024], c_final[2][64][1024] ----------------

__global__ void finalize_kernel(const bf16* __restrict__ h0_last,
                                const float* __restrict__ out_last,
                                const float* __restrict__ c0,
                                const float* __restrict__ c1,
                                float* __restrict__ dst) {
  int i = blockIdx.x * blockDim.x + threadIdx.x;
  if (i < BATCH * HID) {
    dst[i]                      = (float)h0_last[i];
    dst[BATCH * HID + i]        = out_last[i];
    dst[2 * BATCH * HID + i]    = c0[i];
    dst[3 * BATCH * HID + i]    = c1[i];
  }
}

// ---------------- launch ----------------

extern "C" void kernel_launch(void* const* d_in, const int* in_sizes, int n_in,
                              void* d_out, int out_size, void* d_ws, size_t ws_size,
                              hipStream_t stream) {
  const float* x   = (const float*)d_in[0];
  const float* W0  = (const float*)d_in[1];
  const float* R0  = (const float*)d_in[2];
  const float* bi0 = (const float*)d_in[3];
  const float* bh0 = (const float*)d_in[4];
  const float* f0  = (const float*)d_in[5];
  const float* W1  = (const float*)d_in[6];
  const float* R1  = (const float*)d_in[7];
  const float* bi1 = (const float*)d_in[8];
  const float* bh1 = (const float*)d_in[9];
  const float* f1  = (const float*)d_in[10];
  float* out = (float*)d_out;

  char* ws = (char*)d_ws;
  size_t off = 0;
  auto alloc = [&](size_t bytes) {
    char* p = ws + off;
    off += (bytes + 255) & ~(size_t)255;
    return p;
  };
  bf16* W0b = (bf16*)alloc((size_t)GN * KDIM * 2);
  bf16* R0b = (bf16*)alloc((size_t)GN * KDIM * 2);
  bf16* W1b = (bf16*)alloc((size_t)GN * KDIM * 2);
  bf16* R1b = (bf16*)alloc((size_t)GN * KDIM * 2);
  bf16* xb  = (bf16*)alloc((size_t)TB * KDIM * 2);   // x bf16; reused as h1 buffer
  bf16* h0b = (bf16*)alloc((size_t)TB * HID * 2);
  bf16* Gx  = (bf16*)alloc((size_t)TB * GN * 2);
  float* b0c = (float*)alloc(GN * 4);
  float* b1c = (float*)alloc(GN * 4);
  float* fg0 = (float*)alloc(HID * 4);
  float* fg1 = (float*)alloc(HID * 4);
  float* c0s = (float*)alloc((size_t)BATCH * HID * 4);
  float* c1s = (float*)alloc((size_t)BATCH * HID * 4);
  // the next three must stay contiguous (zeroed in one kernel, replay-safe)
  bf16*     zb   = (bf16*)alloc((size_t)BATCH * HID * 2);          // 131072 B
  uint32_t* flg0 = (uint32_t*)alloc((size_t)T_STEPS * 256 * 4);    // 524288 B
  uint32_t* flg1 = (uint32_t*)alloc((size_t)T_STEPS * 512 * 4);    // 1048576 B

  // --- prep ---
  {
    int n4 = GN * KDIM / 4;
    int blocks = (n4 + 255) / 256;
    cvt_f32_to_bf16<<<blocks, 256, 0, stream>>>(W0, W0b, n4);
    cvt_f32_to_bf16<<<blocks, 256, 0, stream>>>(R0, R0b, n4);
    cvt_f32_to_bf16<<<blocks, 256, 0, stream>>>(W1, W1b, n4);
    cvt_f32_to_bf16<<<blocks, 256, 0, stream>>>(R1, R1b, n4);
  }
  {
    int n4 = TB * KDIM / 4;
    cvt_f32_to_bf16<<<(n4 + 255) / 256, 256, 0, stream>>>(x, xb, n4);
  }
  combine_bias<<<(GN + 255) / 256, 256, 0, stream>>>(bi0, bh0, b0c, GN);
  combine_bias<<<(GN + 255) / 256, 256, 0, stream>>>(bi1, bh1, b1c, GN);
  sigmoid_vec<<<(HID + 255) / 256, 256, 0, stream>>>(f0, fg0, HID);
  sigmoid_vec<<<(HID + 255) / 256, 256, 0, stream>>>(f1, fg1, HID);
  {
    // zb + flg0 + flg1 contiguous, zeroed every replay
    int nwords = (BATCH * HID * 2 + T_STEPS * 256 * 4 + T_STEPS * 512 * 4) / 4;
    zero_words<<<(nwords + 255) / 256, 256, 0, stream>>>((uint32_t*)zb, nwords);
  }

  // --- layer-0 x-projection GEMM (off the recurrent critical chain) ---
  gemm_nt_bias<<<dim3(TB / 128, GN / 128), 256, 0, stream>>>(xb, W0b, b0c, Gx);

  // --- fused 2-layer pipelined recurrence (GEMM1 folded into L1 blocks) ---
  fused_persist<<<192, 256, 0, stream>>>(R0b, Gx, fg0, W1b, R1b, b1c, fg1, zb,
                                         h0b, xb, out, c0s, c1s, flg0, flg1);

  // --- finals ---
  finalize_kernel<<<(BATCH * HID + 255) / 256, 256, 0, stream>>>(
      h0b + (size_t)(T_STEPS - 1) * BATCH * HID,
      out + (size_t)(T_STEPS - 1) * BATCH * HID,
      c0s, c1s,
      out + (size_t)T_STEPS * BATCH * HID);
}